// Round 2
// baseline (207.009 us; speedup 1.0000x reference)
//
#include <hip/hip_runtime.h>

typedef __attribute__((ext_vector_type(4))) float f32x4;
typedef __attribute__((ext_vector_type(8))) __bf16 bf16x8;
typedef __attribute__((ext_vector_type(4))) __bf16 bf16x4;

#define DEVINL __device__ __forceinline__

DEVINL void gld16(const void* g, void* l) {
  __builtin_amdgcn_global_load_lds((__attribute__((address_space(1))) void*)(void*)g,
                                   (__attribute__((address_space(3))) void*)l, 16, 0, 0);
}

// ---------------- converts ----------------

__global__ __launch_bounds__(256) void cvt_x(const float* x1, const float* x2, const float* x3,
                                             __bf16* o0, __bf16* o1, __bf16* o2) {
  const int z = blockIdx.y;
  const float* s = z == 0 ? x1 : z == 1 ? x2 : x3;
  __bf16* d = z == 0 ? o0 : z == 1 ? o1 : o2;
  size_t i = (size_t)blockIdx.x * 256 + threadIdx.x;
  f32x4 v = ((const f32x4*)s)[i];
  bf16x4 o;
#pragma unroll
  for (int j = 0; j < 4; ++j) o[j] = (__bf16)v[j];
  ((bf16x4*)d)[i] = o;
}

// W [512 k][512 n] f32  ->  WT [512 n][512 k] bf16
__global__ __launch_bounds__(256) void cvt_w(const float* Wq, const float* Wk, const float* Wv,
                                             const float* Wo, __bf16* WT) {
  __shared__ float t[64][65];
  const int z = blockIdx.z;
  const float* W = z == 0 ? Wq : z == 1 ? Wk : z == 2 ? Wv : Wo;
  __bf16* D = WT + (size_t)z * 512 * 512;
  const int r0 = blockIdx.x * 64, c0 = blockIdx.y * 64;
  const int tx = threadIdx.x & 63, ty = threadIdx.x >> 6;
#pragma unroll
  for (int j = 0; j < 16; ++j)
    t[ty + j * 4][tx] = W[(size_t)(r0 + ty + j * 4) * 512 + c0 + tx];
  __syncthreads();
#pragma unroll
  for (int j = 0; j < 16; ++j)
    D[(size_t)(c0 + ty + j * 4) * 512 + r0 + tx] = (__bf16)t[tx][ty + j * 4];
}

// ---------------- GEMM mainloop: C[128,128] = A[128,K=512] * Bt[128,512]^T, BK=64 ----------------
// LDS tiles 128x64 bf16 (8 x 16B chunks per row), XOR chunk swizzle gc = cs ^ (row&7).

DEVINL void gemm_tile(const __bf16* A, const __bf16* Bt, int m0, int n0,
                      __bf16* As, __bf16* Bs, f32x4 acc[4][4]) {
  const int tid = threadIdx.x, lane = tid & 63, w = tid >> 6;
  const int qd = lane >> 4, r = lane & 15;
  const int wm = w & 1, wn = w >> 1;
  const char* ap[4];
  const char* bp[4];
#pragma unroll
  for (int j = 0; j < 4; ++j) {
    int c = (w * 4 + j) * 64 + lane;  // 0..1023 chunk id
    int row = c >> 3, cs = c & 7;
    int gc = cs ^ (row & 7);
    ap[j] = (const char*)A + (size_t)(m0 + row) * 1024 + gc * 16;
    bp[j] = (const char*)Bt + (size_t)(n0 + row) * 1024 + gc * 16;
  }
  int offA[4][2], offB[4][2];
#pragma unroll
  for (int t = 0; t < 4; ++t)
#pragma unroll
    for (int ks = 0; ks < 2; ++ks) {
      int m = wm * 64 + t * 16 + r;
      offA[t][ks] = m * 128 + (((ks * 4 + qd) ^ (m & 7)) * 16);
      int n = wn * 64 + t * 16 + r;
      offB[t][ks] = n * 128 + (((ks * 4 + qd) ^ (n & 7)) * 16);
    }
  char* AsC = (char*)As;
  char* BsC = (char*)Bs;
  for (int kt = 0; kt < 8; ++kt) {
    __syncthreads();
#pragma unroll
    for (int j = 0; j < 4; ++j) {
      gld16(ap[j] + kt * 128, AsC + (w * 4 + j) * 1024);
      gld16(bp[j] + kt * 128, BsC + (w * 4 + j) * 1024);
    }
    __syncthreads();
#pragma unroll
    for (int ks = 0; ks < 2; ++ks) {
      bf16x8 a[4], b[4];
#pragma unroll
      for (int t = 0; t < 4; ++t) {
        a[t] = *(const bf16x8*)(AsC + offA[t][ks]);
        b[t] = *(const bf16x8*)(BsC + offB[t][ks]);
      }
#pragma unroll
      for (int i = 0; i < 4; ++i)
#pragma unroll
        for (int j2 = 0; j2 < 4; ++j2)
          acc[i][j2] = __builtin_amdgcn_mfma_f32_16x16x32_bf16(a[i], b[j2], acc[i][j2], 0, 0, 0);
    }
  }
}

// z=0: Q[b][h][s][64], z=1: K[b][h][s][64], z=2: Vt[b][h][dv][s]
__global__ __launch_bounds__(256, 2) void gemm_proj(const __bf16* x1b, const __bf16* x2b,
                                                    const __bf16* x3b, const __bf16* WT,
                                                    __bf16* Qo, __bf16* Ko, __bf16* Vto) {
  __shared__ __align__(16) __bf16 As[128 * 64];
  __shared__ __align__(16) __bf16 Bs[128 * 64];
  const int z = blockIdx.z;
  const __bf16* A = z == 0 ? x1b : z == 1 ? x2b : x3b;
  const __bf16* Bt = WT + (size_t)z * 512 * 512;
  // XCD swizzle: 4 n-siblings of an m-tile land on the same XCD (ids differ by 8)
  const int l = blockIdx.x;
  const int sidx = l >> 3;
  const int m0 = ((l & 7) * 8 + (sidx >> 2)) * 128;
  const int n0 = (sidx & 3) * 128;
  f32x4 acc[4][4] = {};
  gemm_tile(A, Bt, m0, n0, As, Bs, acc);
  const int tid = threadIdx.x, lane = tid & 63, w = tid >> 6;
  const int qd = lane >> 4, r = lane & 15, wm = w & 1, wn = w >> 1;
#pragma unroll
  for (int mt = 0; mt < 4; ++mt) {
#pragma unroll
    for (int nt = 0; nt < 4; ++nt) {
      f32x4 v = acc[mt][nt];
      int col = n0 + wn * 64 + nt * 16 + r;
      int h = col >> 6, d = col & 63;
      int mg = m0 + wm * 64 + mt * 16 + qd * 4;
      int b = mg >> 11, s = mg & 2047;
      if (z == 2) {
        bf16x4 pv;
#pragma unroll
        for (int g = 0; g < 4; ++g) pv[g] = (__bf16)v[g];
        *(bf16x4*)(Vto + ((size_t)(b * 8 + h) * 64 + d) * 2048 + s) = pv;
      } else {
        __bf16* O = (z == 0 ? Qo : Ko) + ((size_t)(b * 8 + h) * 2048 + s) * 64 + d;
#pragma unroll
        for (int g = 0; g < 4; ++g) O[(size_t)g * 64] = (__bf16)v[g];
      }
    }
  }
}

__global__ __launch_bounds__(256, 2) void gemm_out(const __bf16* Ob, const __bf16* WoT,
                                                   const float* bo, float* out) {
  __shared__ __align__(16) __bf16 As[128 * 64];
  __shared__ __align__(16) __bf16 Bs[128 * 64];
  const int l = blockIdx.x;
  const int sidx = l >> 3;
  const int m0 = ((l & 7) * 8 + (sidx >> 2)) * 128;
  const int n0 = (sidx & 3) * 128;
  f32x4 acc[4][4] = {};
  gemm_tile(Ob, WoT, m0, n0, As, Bs, acc);
  const int tid = threadIdx.x, lane = tid & 63, w = tid >> 6;
  const int qd = lane >> 4, r = lane & 15, wm = w & 1, wn = w >> 1;
#pragma unroll
  for (int nt = 0; nt < 4; ++nt) {
    int col = n0 + wn * 64 + nt * 16 + r;
    float bv = bo[col];
#pragma unroll
    for (int mt = 0; mt < 4; ++mt) {
      int mg = m0 + wm * 64 + mt * 16 + qd * 4;
#pragma unroll
      for (int g = 0; g < 4; ++g) out[(size_t)(mg + g) * 512 + col] = acc[mt][nt][g] + bv;
    }
  }
}

// ---------------- attention ----------------
// 512 blocks (XCD-swizzled: each XCD owns 4 bh -> K/V fit its L2). Q-tile 128, KV-tile 64,
// double-buffered K/V staging: tile kt+1 gld16s issue BEFORE compute of kt, single barrier/iter.
// No running max (scores bounded, softmax shift-invariant); unnormalized O + rowsum l.
__global__ __launch_bounds__(256, 2) void attn(const __bf16* Q, const __bf16* K,
                                               const __bf16* Vt, __bf16* O) {
  __shared__ __align__(16) __bf16 Qs[128 * 64];
  __shared__ __align__(16) __bf16 Ks[2][64 * 64];
  __shared__ __align__(16) __bf16 Vs[2][64 * 64];
  __shared__ __align__(16) __bf16 Ps[128 * 72];
  const int tid = threadIdx.x, lane = tid & 63, w = tid >> 6;
  const int qd = lane >> 4, r = lane & 15;
  const int id = blockIdx.x;
  const int bh = (id & 7) * 4 + ((id >> 3) >> 4);  // all 16 q-tiles of a bh on one XCD
  const int q0 = ((id >> 3) & 15) * 128;
  const __bf16* Qg = Q + ((size_t)bh * 2048 + q0) * 64;
  const __bf16* Kg = K + (size_t)bh * 2048 * 64;
  const __bf16* Vg = Vt + (size_t)bh * 64 * 2048;
  char* QsC = (char*)Qs;
  char* KsC = (char*)Ks;
  char* VsC = (char*)Vs;
  char* PsC = (char*)Ps;

  // stage Q tile (16KB) + KV tile 0
#pragma unroll
  for (int j = 0; j < 4; ++j) {
    int c = (w * 4 + j) * 64 + lane;
    int m = c >> 3, cs = c & 7, gc = cs ^ (m & 7);
    gld16((const char*)Qg + m * 128 + gc * 16, QsC + (w * 4 + j) * 1024);
  }
#pragma unroll
  for (int j = 0; j < 2; ++j) {
    int c = (w * 2 + j) * 64 + lane;
    int m = c >> 3, cs = c & 7, gc = cs ^ (m & 7);
    gld16((const char*)Kg + (size_t)m * 128 + gc * 16, KsC + (w * 2 + j) * 1024);
    gld16((const char*)Vg + (size_t)m * 4096 + gc * 16, VsC + (w * 2 + j) * 1024);
  }
  __syncthreads();

  bf16x8 qf[2][2];
#pragma unroll
  for (int mt = 0; mt < 2; ++mt)
#pragma unroll
    for (int ks = 0; ks < 2; ++ks) {
      int m = w * 32 + mt * 16 + r;
      qf[mt][ks] = *(const bf16x8*)(QsC + m * 128 + ((ks * 4 + qd) ^ (m & 7)) * 16);
    }

  int offKV[4][2];
#pragma unroll
  for (int t = 0; t < 4; ++t)
#pragma unroll
    for (int ks = 0; ks < 2; ++ks) {
      int n = t * 16 + r;
      offKV[t][ks] = n * 128 + ((ks * 4 + qd) ^ (n & 7)) * 16;
    }

  f32x4 oacc[2][4] = {};
  float lpart[2][4] = {};

  for (int kt = 0; kt < 32; ++kt) {
    const int cur = kt & 1;
    // prefetch tile kt+1 into the other buffer (overlaps compute below)
    if (kt < 31) {
#pragma unroll
      for (int j = 0; j < 2; ++j) {
        int c = (w * 2 + j) * 64 + lane;
        int m = c >> 3, cs = c & 7, gc = cs ^ (m & 7);
        gld16((const char*)Kg + (size_t)((kt + 1) * 64 + m) * 128 + gc * 16,
              KsC + (cur ^ 1) * 8192 + (w * 2 + j) * 1024);
        gld16((const char*)Vg + (size_t)m * 4096 + (kt + 1) * 128 + gc * 16,
              VsC + (cur ^ 1) * 8192 + (w * 2 + j) * 1024);
      }
    }
    const char* Kb = KsC + cur * 8192;
    const char* Vb = VsC + cur * 8192;

    // S = Q K^T  (wave: 32 q-rows x 64 keys)
    f32x4 sf[2][4] = {};
#pragma unroll
    for (int nt = 0; nt < 4; ++nt) {
      bf16x8 kf0 = *(const bf16x8*)(Kb + offKV[nt][0]);
      bf16x8 kf1 = *(const bf16x8*)(Kb + offKV[nt][1]);
#pragma unroll
      for (int mt = 0; mt < 2; ++mt) {
        sf[mt][nt] = __builtin_amdgcn_mfma_f32_16x16x32_bf16(qf[mt][0], kf0, sf[mt][nt], 0, 0, 0);
        sf[mt][nt] = __builtin_amdgcn_mfma_f32_16x16x32_bf16(qf[mt][1], kf1, sf[mt][nt], 0, 0, 0);
      }
    }
    // exp, rowsum partials, P -> LDS (C-layout -> A-layout round trip, own rows only)
#pragma unroll
    for (int mt = 0; mt < 2; ++mt) {
      int rowbase = w * 32 + mt * 16 + qd * 4;
#pragma unroll
      for (int nt = 0; nt < 4; ++nt) {
#pragma unroll
        for (int g = 0; g < 4; ++g) {
          float p = __expf(sf[mt][nt][g] * 0.125f);
          lpart[mt][g] += p;
          Ps[(rowbase + g) * 72 + nt * 16 + r] = (__bf16)p;
        }
      }
    }
    // O += P V
#pragma unroll
    for (int mt = 0; mt < 2; ++mt) {
      int prow = w * 32 + mt * 16 + r;
      bf16x8 pf0 = *(const bf16x8*)(PsC + prow * 144 + qd * 16);
      bf16x8 pf1 = *(const bf16x8*)(PsC + prow * 144 + 64 + qd * 16);
#pragma unroll
      for (int dvt = 0; dvt < 4; ++dvt) {
        bf16x8 vf0 = *(const bf16x8*)(Vb + offKV[dvt][0]);
        bf16x8 vf1 = *(const bf16x8*)(Vb + offKV[dvt][1]);
        oacc[mt][dvt] = __builtin_amdgcn_mfma_f32_16x16x32_bf16(pf0, vf0, oacc[mt][dvt], 0, 0, 0);
        oacc[mt][dvt] = __builtin_amdgcn_mfma_f32_16x16x32_bf16(pf1, vf1, oacc[mt][dvt], 0, 0, 0);
      }
    }
    __syncthreads();  // all waves done with buf[cur]; drains prefetch of buf[cur^1]
  }

  const int b = bh >> 3, h = bh & 7;
#pragma unroll
  for (int mt = 0; mt < 2; ++mt) {
#pragma unroll
    for (int g = 0; g < 4; ++g) {
      float l = lpart[mt][g];
      l += __shfl_xor(l, 1, 64);
      l += __shfl_xor(l, 2, 64);
      l += __shfl_xor(l, 4, 64);
      l += __shfl_xor(l, 8, 64);
      float inv = 1.0f / l;
      int s = q0 + w * 32 + mt * 16 + qd * 4 + g;
#pragma unroll
      for (int dvt = 0; dvt < 4; ++dvt)
        O[((size_t)b * 2048 + s) * 512 + h * 64 + dvt * 16 + r] =
            (__bf16)(oacc[mt][dvt][g] * inv);
    }
  }
}

// ---------------- host ----------------

extern "C" void kernel_launch(void* const* d_in, const int* in_sizes, int n_in,
                              void* d_out, int out_size, void* d_ws, size_t ws_size,
                              hipStream_t stream) {
  const float* x1 = (const float*)d_in[0];
  const float* x2 = (const float*)d_in[1];
  const float* x3 = (const float*)d_in[2];
  const float* Wq = (const float*)d_in[3];
  const float* Wk = (const float*)d_in[4];
  const float* Wv = (const float*)d_in[5];
  const float* Wo = (const float*)d_in[6];
  const float* bo = (const float*)d_in[7];
  float* out = (float*)d_out;
  char* ws = (char*)d_ws;
  const size_t MB = 1ull << 20;
  __bf16* x1b = (__bf16*)(ws);
  __bf16* x2b = (__bf16*)(ws + 8 * MB);
  __bf16* x3b = (__bf16*)(ws + 16 * MB);
  __bf16* WT = (__bf16*)(ws + 24 * MB);
  __bf16* Qb = (__bf16*)(ws + 26 * MB);
  __bf16* Kb = (__bf16*)(ws + 34 * MB);
  __bf16* Vtb = (__bf16*)(ws + 42 * MB);
  __bf16* Ob = (__bf16*)(ws + 50 * MB);

  cvt_x<<<dim3(4096, 3), 256, 0, stream>>>(x1, x2, x3, x1b, x2b, x3b);
  cvt_w<<<dim3(8, 8, 4), 256, 0, stream>>>(Wq, Wk, Wv, Wo, WT);
  gemm_proj<<<dim3(256, 1, 3), 256, 0, stream>>>(x1b, x2b, x3b, WT, Qb, Kb, Vtb);
  attn<<<dim3(512), 256, 0, stream>>>(Qb, Kb, Vtb, Ob);
  gemm_out<<<dim3(256), 256, 0, stream>>>(Ob, WT + 3ull * 512 * 512, bo, out);
}

// Round 3
// 201.488 us; speedup vs baseline: 1.0274x; 1.0274x over previous
//
#include <hip/hip_runtime.h>

typedef __attribute__((ext_vector_type(4))) float f32x4;
typedef __attribute__((ext_vector_type(8))) __bf16 bf16x8;
typedef __attribute__((ext_vector_type(4))) __bf16 bf16x4;

#define DEVINL __device__ __forceinline__

DEVINL void gld16(const void* g, void* l) {
  __builtin_amdgcn_global_load_lds((__attribute__((address_space(1))) void*)(void*)g,
                                   (__attribute__((address_space(3))) void*)l, 16, 0, 0);
}

// ---------------- converts ----------------

__global__ __launch_bounds__(256) void cvt_x(const float* x1, const float* x2, const float* x3,
                                             __bf16* o0, __bf16* o1, __bf16* o2) {
  const int z = blockIdx.y;
  const float* s = z == 0 ? x1 : z == 1 ? x2 : x3;
  __bf16* d = z == 0 ? o0 : z == 1 ? o1 : o2;
  size_t i = (size_t)blockIdx.x * 256 + threadIdx.x;
  f32x4 v = ((const f32x4*)s)[i];
  bf16x4 o;
#pragma unroll
  for (int j = 0; j < 4; ++j) o[j] = (__bf16)v[j];
  ((bf16x4*)d)[i] = o;
}

// W [512 k][512 n] f32  ->  WT [512 n][512 k] bf16
__global__ __launch_bounds__(256) void cvt_w(const float* Wq, const float* Wk, const float* Wv,
                                             const float* Wo, __bf16* WT) {
  __shared__ float t[64][65];
  const int z = blockIdx.z;
  const float* W = z == 0 ? Wq : z == 1 ? Wk : z == 2 ? Wv : Wo;
  __bf16* D = WT + (size_t)z * 512 * 512;
  const int r0 = blockIdx.x * 64, c0 = blockIdx.y * 64;
  const int tx = threadIdx.x & 63, ty = threadIdx.x >> 6;
#pragma unroll
  for (int j = 0; j < 16; ++j)
    t[ty + j * 4][tx] = W[(size_t)(r0 + ty + j * 4) * 512 + c0 + tx];
  __syncthreads();
#pragma unroll
  for (int j = 0; j < 16; ++j)
    D[(size_t)(c0 + ty + j * 4) * 512 + r0 + tx] = (__bf16)t[tx][ty + j * 4];
}

// ---------------- GEMM mainloop: C[128,128] = A[128,K=512] * Bt[128,512]^T, BK=64 ----------------

DEVINL void gemm_tile(const __bf16* A, const __bf16* Bt, int m0, int n0,
                      __bf16* As, __bf16* Bs, f32x4 acc[4][4]) {
  const int tid = threadIdx.x, lane = tid & 63, w = tid >> 6;
  const int qd = lane >> 4, r = lane & 15;
  const int wm = w & 1, wn = w >> 1;
  const char* ap[4];
  const char* bp[4];
#pragma unroll
  for (int j = 0; j < 4; ++j) {
    int c = (w * 4 + j) * 64 + lane;
    int row = c >> 3, cs = c & 7;
    int gc = cs ^ (row & 7);
    ap[j] = (const char*)A + (size_t)(m0 + row) * 1024 + gc * 16;
    bp[j] = (const char*)Bt + (size_t)(n0 + row) * 1024 + gc * 16;
  }
  int offA[4][2], offB[4][2];
#pragma unroll
  for (int t = 0; t < 4; ++t)
#pragma unroll
    for (int ks = 0; ks < 2; ++ks) {
      int m = wm * 64 + t * 16 + r;
      offA[t][ks] = m * 128 + (((ks * 4 + qd) ^ (m & 7)) * 16);
      int n = wn * 64 + t * 16 + r;
      offB[t][ks] = n * 128 + (((ks * 4 + qd) ^ (n & 7)) * 16);
    }
  char* AsC = (char*)As;
  char* BsC = (char*)Bs;
  for (int kt = 0; kt < 8; ++kt) {
    __syncthreads();
#pragma unroll
    for (int j = 0; j < 4; ++j) {
      gld16(ap[j] + kt * 128, AsC + (w * 4 + j) * 1024);
      gld16(bp[j] + kt * 128, BsC + (w * 4 + j) * 1024);
    }
    __syncthreads();
#pragma unroll
    for (int ks = 0; ks < 2; ++ks) {
      bf16x8 a[4], b[4];
#pragma unroll
      for (int t = 0; t < 4; ++t) {
        a[t] = *(const bf16x8*)(AsC + offA[t][ks]);
        b[t] = *(const bf16x8*)(BsC + offB[t][ks]);
      }
#pragma unroll
      for (int i = 0; i < 4; ++i)
#pragma unroll
        for (int j2 = 0; j2 < 4; ++j2)
          acc[i][j2] = __builtin_amdgcn_mfma_f32_16x16x32_bf16(a[i], b[j2], acc[i][j2], 0, 0, 0);
    }
  }
}

// z=0: Q[b][h][s][64] (pre-scaled by 0.125/ln2), z=1: K[b][h][s][64], z=2: Vt[b][h][dv][s]
__global__ __launch_bounds__(256, 2) void gemm_proj(const __bf16* x1b, const __bf16* x2b,
                                                    const __bf16* x3b, const __bf16* WT,
                                                    __bf16* Qo, __bf16* Ko, __bf16* Vto) {
  __shared__ __align__(16) char smem[34816];  // As(16K) + Bs(16K) in loop; T[128][136] in epilogue
  __bf16* As = (__bf16*)smem;
  __bf16* Bs = (__bf16*)(smem + 16384);
  const int z = blockIdx.z;
  const __bf16* A = z == 0 ? x1b : z == 1 ? x2b : x3b;
  const __bf16* Bt = WT + (size_t)z * 512 * 512;
  const int l = blockIdx.x;
  const int sidx = l >> 3;
  const int m0 = ((l & 7) * 8 + (sidx >> 2)) * 128;
  const int n0 = (sidx & 3) * 128;
  f32x4 acc[4][4] = {};
  gemm_tile(A, Bt, m0, n0, As, Bs, acc);
  const int tid = threadIdx.x, lane = tid & 63, w = tid >> 6;
  const int qd = lane >> 4, r = lane & 15, wm = w & 1, wn = w >> 1;
  const int b = m0 >> 11, sbase = m0 & 2047;
  if (z == 2) {
    __syncthreads();  // done reading As/Bs; reuse as T[dv 128][s 136-stride]
    char* T = smem;
#pragma unroll
    for (int mt = 0; mt < 4; ++mt)
#pragma unroll
      for (int nt = 0; nt < 4; ++nt) {
        int dv = wn * 64 + nt * 16 + r;
        int sl = wm * 64 + mt * 16 + qd * 4;
        bf16x4 p4;
#pragma unroll
        for (int g = 0; g < 4; ++g) p4[g] = (__bf16)acc[mt][nt][g];
        *(bf16x4*)(T + (size_t)dv * 272 + sl * 2) = p4;
      }
    __syncthreads();
#pragma unroll
    for (int p2 = 0; p2 < 2; ++p2) {
      int dvrow = p2 * 64 + (tid >> 2);
      int col = n0 + dvrow, h = col >> 6, d = col & 63;
      __bf16* dst = Vto + ((size_t)(b * 8 + h) * 64 + d) * 2048 + sbase + (tid & 3) * 8;
#pragma unroll
      for (int j = 0; j < 4; ++j) {
        bf16x8 vv = *(const bf16x8*)(T + (size_t)dvrow * 272 + (tid & 3) * 16 + j * 64);
        *(bf16x8*)(dst + j * 32) = vv;
      }
    }
  } else {
    const float qscale = 0.18033688f;  // 0.125 / ln(2): scores*0.125 via exp2
#pragma unroll
    for (int mt = 0; mt < 4; ++mt) {
#pragma unroll
      for (int nt = 0; nt < 4; ++nt) {
        f32x4 v = acc[mt][nt];
        if (z == 0) {
#pragma unroll
          for (int g = 0; g < 4; ++g) v[g] *= qscale;
        }
        int col = n0 + wn * 64 + nt * 16 + r;
        int h = col >> 6, d = col & 63;
        int s = sbase + wm * 64 + mt * 16 + qd * 4;
        __bf16* O = (z == 0 ? Qo : Ko) + ((size_t)(b * 8 + h) * 2048 + s) * 64 + d;
#pragma unroll
        for (int g = 0; g < 4; ++g) O[(size_t)g * 64] = (__bf16)v[g];
      }
    }
  }
}

// ---------------- gemm_out: out[8192,512] = Ob @ WoT^T + bo, tile 64x128, grid 512 ----------------
__global__ __launch_bounds__(256, 2) void gemm_out(const __bf16* Ob, const __bf16* WoT,
                                                   const float* bo, float* out) {
  __shared__ __align__(16) __bf16 As[64 * 64];
  __shared__ __align__(16) __bf16 Bs[128 * 64];
  const int tid = threadIdx.x, lane = tid & 63, w = tid >> 6;
  const int qd = lane >> 4, r = lane & 15, wm = w & 1, wn = w >> 1;
  const int id = blockIdx.x;
  const int rest = id >> 3;
  const int m0 = ((id & 7) * 16 + (rest & 15)) * 64;
  const int n0 = (rest >> 4) * 128;
  const char* ap[2];
  const char* bp[4];
#pragma unroll
  for (int j = 0; j < 2; ++j) {
    int c = (w * 2 + j) * 64 + lane;
    int row = c >> 3, gc = (c & 7) ^ (row & 7);
    ap[j] = (const char*)Ob + (size_t)(m0 + row) * 1024 + gc * 16;
  }
#pragma unroll
  for (int j = 0; j < 4; ++j) {
    int c = (w * 4 + j) * 64 + lane;
    int row = c >> 3, gc = (c & 7) ^ (row & 7);
    bp[j] = (const char*)WoT + (size_t)(n0 + row) * 1024 + gc * 16;
  }
  int offA[2][2], offB[4][2];
#pragma unroll
  for (int ks = 0; ks < 2; ++ks) {
#pragma unroll
    for (int t = 0; t < 2; ++t) {
      int m = wm * 32 + t * 16 + r;
      offA[t][ks] = m * 128 + (((ks * 4 + qd) ^ (m & 7)) * 16);
    }
#pragma unroll
    for (int t = 0; t < 4; ++t) {
      int n = wn * 64 + t * 16 + r;
      offB[t][ks] = n * 128 + (((ks * 4 + qd) ^ (n & 7)) * 16);
    }
  }
  char* AsC = (char*)As;
  char* BsC = (char*)Bs;
  f32x4 acc[2][4] = {};
  for (int kt = 0; kt < 8; ++kt) {
    __syncthreads();
#pragma unroll
    for (int j = 0; j < 2; ++j) gld16(ap[j] + kt * 128, AsC + (w * 2 + j) * 1024);
#pragma unroll
    for (int j = 0; j < 4; ++j) gld16(bp[j] + kt * 128, BsC + (w * 4 + j) * 1024);
    __syncthreads();
#pragma unroll
    for (int ks = 0; ks < 2; ++ks) {
      bf16x8 a[2], b[4];
#pragma unroll
      for (int t = 0; t < 2; ++t) a[t] = *(const bf16x8*)(AsC + offA[t][ks]);
#pragma unroll
      for (int t = 0; t < 4; ++t) b[t] = *(const bf16x8*)(BsC + offB[t][ks]);
#pragma unroll
      for (int i = 0; i < 2; ++i)
#pragma unroll
        for (int j2 = 0; j2 < 4; ++j2)
          acc[i][j2] = __builtin_amdgcn_mfma_f32_16x16x32_bf16(a[i], b[j2], acc[i][j2], 0, 0, 0);
    }
  }
#pragma unroll
  for (int nt = 0; nt < 4; ++nt) {
    int col = n0 + wn * 64 + nt * 16 + r;
    float bv = bo[col];
#pragma unroll
    for (int mt = 0; mt < 2; ++mt) {
      int mg = m0 + wm * 32 + mt * 16 + qd * 4;
#pragma unroll
      for (int g = 0; g < 4; ++g) out[(size_t)(mg + g) * 512 + col] = acc[mt][nt][g] + bv;
    }
  }
}

// ---------------- attention ----------------
// Grid 1024 = 8 XCD x (4 bh x 2 kv-halves x 16 q-tiles). Q-tile 128, KV-tile 64, 16 iters/block.
// Computes S^T = K·Q^T so P exits MFMA with keys on the per-lane reg axis -> packed bf16x4 LDS
// writes into Ps[q][key]. No running max (scores bounded; exp2 with scale folded into Q).
// Writes unnormalized bf16 O-partial + f32 rowsum; combine kernel normalizes.
__global__ __launch_bounds__(256, 3) void attn(const __bf16* Q, const __bf16* K,
                                               const __bf16* Vt, __bf16* Opart, float* Lp) {
  __shared__ __align__(16) __bf16 Qs[128 * 64];
  __shared__ __align__(16) __bf16 Ks[64 * 64];
  __shared__ __align__(16) __bf16 Vs[64 * 64];
  __shared__ __align__(16) __bf16 Ps[128 * 72];  // row stride 144 B
  const int tid = threadIdx.x, lane = tid & 63, w = tid >> 6;
  const int qd = lane >> 4, r = lane & 15;
  const int id = blockIdx.x;
  const int rest = id >> 3;
  const int bh = (id & 7) * 4 + (rest >> 5);
  const int kvh = (rest >> 4) & 1;
  const int q0 = (rest & 15) * 128;
  const __bf16* Qg = Q + ((size_t)bh * 2048 + q0) * 64;
  const __bf16* Kg = K + (size_t)bh * 2048 * 64;
  const __bf16* Vg = Vt + (size_t)bh * 64 * 2048;
  char* QsC = (char*)Qs;
  char* KsC = (char*)Ks;
  char* VsC = (char*)Vs;
  char* PsC = (char*)Ps;

  // stage Q tile (16KB)
#pragma unroll
  for (int j = 0; j < 4; ++j) {
    int c = (w * 4 + j) * 64 + lane;
    int m = c >> 3, gc = (c & 7) ^ (m & 7);
    gld16((const char*)Qg + m * 128 + gc * 16, QsC + (w * 4 + j) * 1024);
  }
  __syncthreads();

  // Q fragments (B-operand: n=q on lane&15, k=d on qd*8+j)
  bf16x8 qf[2][2];
#pragma unroll
  for (int mt = 0; mt < 2; ++mt)
#pragma unroll
    for (int ks = 0; ks < 2; ++ks) {
      int m = w * 32 + mt * 16 + r;
      qf[mt][ks] = *(const bf16x8*)(QsC + m * 128 + ((ks * 4 + qd) ^ (m & 7)) * 16);
    }

  int offKV[4][2];
#pragma unroll
  for (int t = 0; t < 4; ++t)
#pragma unroll
    for (int ks = 0; ks < 2; ++ks) {
      int n = t * 16 + r;
      offKV[t][ks] = n * 128 + ((ks * 4 + qd) ^ (n & 7)) * 16;
    }

  f32x4 oacc[2][4] = {};
  float lpart[2] = {0.f, 0.f};

  const int kt0 = kvh * 16;
  for (int kt = kt0; kt < kt0 + 16; ++kt) {
    __syncthreads();
#pragma unroll
    for (int j = 0; j < 2; ++j) {
      int c = (w * 2 + j) * 64 + lane;
      int m = c >> 3, gc = (c & 7) ^ (m & 7);
      gld16((const char*)Kg + (size_t)(kt * 64 + m) * 128 + gc * 16, KsC + (w * 2 + j) * 1024);
      gld16((const char*)Vg + (size_t)m * 4096 + kt * 128 + gc * 16, VsC + (w * 2 + j) * 1024);
    }
    __syncthreads();

    // S^T = K · Q^T : D[m=key][n=q]  (A=K frags, B=Q frags)
    f32x4 sf[2][4] = {};
#pragma unroll
    for (int nt = 0; nt < 4; ++nt) {
      bf16x8 kf0 = *(const bf16x8*)(KsC + offKV[nt][0]);
      bf16x8 kf1 = *(const bf16x8*)(KsC + offKV[nt][1]);
#pragma unroll
      for (int mt = 0; mt < 2; ++mt) {
        sf[mt][nt] = __builtin_amdgcn_mfma_f32_16x16x32_bf16(kf0, qf[mt][0], sf[mt][nt], 0, 0, 0);
        sf[mt][nt] = __builtin_amdgcn_mfma_f32_16x16x32_bf16(kf1, qf[mt][1], sf[mt][nt], 0, 0, 0);
      }
    }
    // exp2, rowsum partial, packed P write: lane holds keys nt*16+qd*4+{0..3} of q-row (w*32+mt*16+r)
#pragma unroll
    for (int mt = 0; mt < 2; ++mt) {
      int q = w * 32 + mt * 16 + r;
#pragma unroll
      for (int nt = 0; nt < 4; ++nt) {
        bf16x4 p4;
#pragma unroll
        for (int g = 0; g < 4; ++g) {
          float p = __builtin_exp2f(sf[mt][nt][g]);
          lpart[mt] += p;
          p4[g] = (__bf16)p;
        }
        *(bf16x4*)(PsC + q * 144 + nt * 32 + qd * 8) = p4;
      }
    }
    // O += P V  (P rows are wave-private: write->read needs only lgkmcnt, no barrier)
#pragma unroll
    for (int mt = 0; mt < 2; ++mt) {
      int prow = w * 32 + mt * 16 + r;
      bf16x8 pf0 = *(const bf16x8*)(PsC + prow * 144 + qd * 16);
      bf16x8 pf1 = *(const bf16x8*)(PsC + prow * 144 + 64 + qd * 16);
#pragma unroll
      for (int dvt = 0; dvt < 4; ++dvt) {
        bf16x8 vf0 = *(const bf16x8*)(VsC + offKV[dvt][0]);
        bf16x8 vf1 = *(const bf16x8*)(VsC + offKV[dvt][1]);
        oacc[mt][dvt] = __builtin_amdgcn_mfma_f32_16x16x32_bf16(pf0, vf0, oacc[mt][dvt], 0, 0, 0);
        oacc[mt][dvt] = __builtin_amdgcn_mfma_f32_16x16x32_bf16(pf1, vf1, oacc[mt][dvt], 0, 0, 0);
      }
    }
  }

  // rowsum: lane (qd,r) holds partial for q = w*32+mt*16+r over its 16 keys/iter; reduce across qd
  const size_t pbase = (size_t)(kvh * 32 + bh) * 2048;
#pragma unroll
  for (int mt = 0; mt < 2; ++mt) {
    float lsum = lpart[mt];
    lsum += __shfl_xor(lsum, 16, 64);
    lsum += __shfl_xor(lsum, 32, 64);
    if (lane < 16) Lp[pbase + q0 + w * 32 + mt * 16 + r] = lsum;
  }
  // unnormalized O partial (bf16): lane holds q = w*32+mt*16+qd*4+g, dv = dvt*16+r
  __bf16* Ob0 = Opart + pbase * 64;
#pragma unroll
  for (int mt = 0; mt < 2; ++mt) {
#pragma unroll
    for (int g = 0; g < 4; ++g) {
      int s = q0 + w * 32 + mt * 16 + qd * 4 + g;
#pragma unroll
      for (int dvt = 0; dvt < 4; ++dvt)
        Ob0[(size_t)s * 64 + dvt * 16 + r] = (__bf16)oacc[mt][dvt][g];
    }
  }
}

// combine the two kv-half partials -> Ob[b][s][h*64+dv] bf16
__global__ __launch_bounds__(256) void combine(const __bf16* Op, const float* Lp, __bf16* Ob) {
  int c = blockIdx.x * 256 + threadIdx.x;  // 524288 chunks of 8 elems
  int bhs = c >> 3;
  int dv0 = (c & 7) * 8;
  size_t e = (size_t)bhs * 64 + dv0;
  bf16x8 a = *(const bf16x8*)(Op + e);
  bf16x8 b2 = *(const bf16x8*)(Op + ((size_t)32 * 2048 * 64) + e);
  float inv = 1.0f / (Lp[bhs] + Lp[bhs + 65536]);
  int bh = bhs >> 11, s = bhs & 2047, b = bh >> 3, h = bh & 7;
  bf16x8 o;
#pragma unroll
  for (int j = 0; j < 8; ++j) o[j] = (__bf16)(((float)a[j] + (float)b2[j]) * inv);
  *(bf16x8*)(Ob + ((size_t)(b * 2048 + s)) * 512 + h * 64 + dv0) = o;
}

// ---------------- host ----------------

extern "C" void kernel_launch(void* const* d_in, const int* in_sizes, int n_in,
                              void* d_out, int out_size, void* d_ws, size_t ws_size,
                              hipStream_t stream) {
  const float* x1 = (const float*)d_in[0];
  const float* x2 = (const float*)d_in[1];
  const float* x3 = (const float*)d_in[2];
  const float* Wq = (const float*)d_in[3];
  const float* Wk = (const float*)d_in[4];
  const float* Wv = (const float*)d_in[5];
  const float* Wo = (const float*)d_in[6];
  const float* bo = (const float*)d_in[7];
  float* out = (float*)d_out;
  char* ws = (char*)d_ws;
  const size_t MB = 1ull << 20;
  __bf16* x1b = (__bf16*)(ws);
  __bf16* x2b = (__bf16*)(ws + 8 * MB);
  __bf16* x3b = (__bf16*)(ws + 16 * MB);
  __bf16* WT = (__bf16*)(ws + 24 * MB);
  __bf16* Qb = (__bf16*)(ws + 26 * MB);
  __bf16* Kb = (__bf16*)(ws + 34 * MB);
  __bf16* Vtb = (__bf16*)(ws + 42 * MB);
  __bf16* Ob = (__bf16*)(ws + 50 * MB);
  __bf16* Opart = (__bf16*)(ws + 58 * MB);
  float* Lp = (float*)(ws + 74 * MB);

  cvt_x<<<dim3(4096, 3), 256, 0, stream>>>(x1, x2, x3, x1b, x2b, x3b);
  cvt_w<<<dim3(8, 8, 4), 256, 0, stream>>>(Wq, Wk, Wv, Wo, WT);
  gemm_proj<<<dim3(256, 1, 3), 256, 0, stream>>>(x1b, x2b, x3b, WT, Qb, Kb, Vtb);
  attn<<<dim3(1024), 256, 0, stream>>>(Qb, Kb, Vtb, Opart, Lp);
  combine<<<dim3(2048), 256, 0, stream>>>(Opart, Lp, Ob);
  gemm_out<<<dim3(512), 256, 0, stream>>>(Ob, WT + 3ull * 512 * 512, bo, out);
}

// Round 4
// 183.193 us; speedup vs baseline: 1.1300x; 1.0999x over previous
//
#include <hip/hip_runtime.h>

typedef __attribute__((ext_vector_type(4))) float f32x4;
typedef __attribute__((ext_vector_type(8))) __bf16 bf16x8;
typedef __attribute__((ext_vector_type(4))) __bf16 bf16x4;

#define DEVINL __device__ __forceinline__

DEVINL void gld16(const void* g, void* l) {
  __builtin_amdgcn_global_load_lds((__attribute__((address_space(1))) void*)(void*)g,
                                   (__attribute__((address_space(3))) void*)l, 16, 0, 0);
}

// ---------------- converts (fused: x-cast blocks + W-transpose blocks) ----------------

__global__ __launch_bounds__(256) void cvt_all(const float* x1, const float* x2, const float* x3,
                                               const float* Wq, const float* Wk, const float* Wv,
                                               const float* Wo, __bf16* o0, __bf16* o1, __bf16* o2,
                                               __bf16* WT) {
  __shared__ float t[64][65];
  const int bx = blockIdx.x;
  if (bx < 12288) {
    const int z = bx >> 12;
    const float* s = z == 0 ? x1 : z == 1 ? x2 : x3;
    __bf16* d = z == 0 ? o0 : z == 1 ? o1 : o2;
    size_t i = (size_t)(bx & 4095) * 256 + threadIdx.x;
    f32x4 v = ((const f32x4*)s)[i];
    bf16x4 o;
#pragma unroll
    for (int j = 0; j < 4; ++j) o[j] = (__bf16)v[j];
    ((bf16x4*)d)[i] = o;
  } else {
    const int l = bx - 12288;  // 256 blocks: z(4) x r(8) x c(8)
    const int z = l >> 6;
    const float* W = z == 0 ? Wq : z == 1 ? Wk : z == 2 ? Wv : Wo;
    __bf16* D = WT + (size_t)z * 512 * 512;
    const int r0 = ((l >> 3) & 7) * 64, c0 = (l & 7) * 64;
    const int tx = threadIdx.x & 63, ty = threadIdx.x >> 6;
#pragma unroll
    for (int j = 0; j < 16; ++j)
      t[ty + j * 4][tx] = W[(size_t)(r0 + ty + j * 4) * 512 + c0 + tx];
    __syncthreads();
#pragma unroll
    for (int j = 0; j < 16; ++j)
      D[(size_t)(c0 + ty + j * 4) * 512 + r0 + tx] = (__bf16)t[tx][ty + j * 4];
  }
}

// ---------------- GEMM mainloop: C[128,128] = A[128,K=512] * Bt[128,512]^T, BK=64 ----------------

DEVINL void gemm_tile(const __bf16* A, const __bf16* Bt, int m0, int n0,
                      __bf16* As, __bf16* Bs, f32x4 acc[4][4]) {
  const int tid = threadIdx.x, lane = tid & 63, w = tid >> 6;
  const int qd = lane >> 4, r = lane & 15;
  const int wm = w & 1, wn = w >> 1;
  const char* ap[4];
  const char* bp[4];
#pragma unroll
  for (int j = 0; j < 4; ++j) {
    int c = (w * 4 + j) * 64 + lane;
    int row = c >> 3, cs = c & 7;
    int gc = cs ^ (row & 7);
    ap[j] = (const char*)A + (size_t)(m0 + row) * 1024 + gc * 16;
    bp[j] = (const char*)Bt + (size_t)(n0 + row) * 1024 + gc * 16;
  }
  int offA[4][2], offB[4][2];
#pragma unroll
  for (int t = 0; t < 4; ++t)
#pragma unroll
    for (int ks = 0; ks < 2; ++ks) {
      int m = wm * 64 + t * 16 + r;
      offA[t][ks] = m * 128 + (((ks * 4 + qd) ^ (m & 7)) * 16);
      int n = wn * 64 + t * 16 + r;
      offB[t][ks] = n * 128 + (((ks * 4 + qd) ^ (n & 7)) * 16);
    }
  char* AsC = (char*)As;
  char* BsC = (char*)Bs;
  for (int kt = 0; kt < 8; ++kt) {
    __syncthreads();
#pragma unroll
    for (int j = 0; j < 4; ++j) {
      gld16(ap[j] + kt * 128, AsC + (w * 4 + j) * 1024);
      gld16(bp[j] + kt * 128, BsC + (w * 4 + j) * 1024);
    }
    __syncthreads();
#pragma unroll
    for (int ks = 0; ks < 2; ++ks) {
      bf16x8 a[4], b[4];
#pragma unroll
      for (int t = 0; t < 4; ++t) {
        a[t] = *(const bf16x8*)(AsC + offA[t][ks]);
        b[t] = *(const bf16x8*)(BsC + offB[t][ks]);
      }
#pragma unroll
      for (int i = 0; i < 4; ++i)
#pragma unroll
        for (int j2 = 0; j2 < 4; ++j2)
          acc[i][j2] = __builtin_amdgcn_mfma_f32_16x16x32_bf16(a[i], b[j2], acc[i][j2], 0, 0, 0);
    }
  }
}

// z=0: Q[b][h][s][64] (pre-scaled by 0.125/ln2), z=1: K[b][h][s][64], z=2: Vt[b][h][dv][s]
__global__ __launch_bounds__(256, 3) void gemm_proj(const __bf16* x1b, const __bf16* x2b,
                                                    const __bf16* x3b, const __bf16* WT,
                                                    __bf16* Qo, __bf16* Ko, __bf16* Vto) {
  __shared__ __align__(16) char smem[34816];  // As(16K) + Bs(16K) in loop; T[128][136] in epilogue
  __bf16* As = (__bf16*)smem;
  __bf16* Bs = (__bf16*)(smem + 16384);
  const int z = blockIdx.z;
  const __bf16* A = z == 0 ? x1b : z == 1 ? x2b : x3b;
  const __bf16* Bt = WT + (size_t)z * 512 * 512;
  const int l = blockIdx.x;
  const int sidx = l >> 3;
  const int m0 = ((l & 7) * 8 + (sidx >> 2)) * 128;
  const int n0 = (sidx & 3) * 128;
  f32x4 acc[4][4] = {};
  gemm_tile(A, Bt, m0, n0, As, Bs, acc);
  const int tid = threadIdx.x, lane = tid & 63, w = tid >> 6;
  const int qd = lane >> 4, r = lane & 15, wm = w & 1, wn = w >> 1;
  const int b = m0 >> 11, sbase = m0 & 2047;
  if (z == 2) {
    __syncthreads();  // done reading As/Bs; reuse as T[dv 128][s 136-stride]
    char* T = smem;
#pragma unroll
    for (int mt = 0; mt < 4; ++mt)
#pragma unroll
      for (int nt = 0; nt < 4; ++nt) {
        int dv = wn * 64 + nt * 16 + r;
        int sl = wm * 64 + mt * 16 + qd * 4;
        bf16x4 p4;
#pragma unroll
        for (int g = 0; g < 4; ++g) p4[g] = (__bf16)acc[mt][nt][g];
        *(bf16x4*)(T + (size_t)dv * 272 + sl * 2) = p4;
      }
    __syncthreads();
#pragma unroll
    for (int p2 = 0; p2 < 2; ++p2) {
      int dvrow = p2 * 64 + (tid >> 2);
      int col = n0 + dvrow, h = col >> 6, d = col & 63;
      __bf16* dst = Vto + ((size_t)(b * 8 + h) * 64 + d) * 2048 + sbase + (tid & 3) * 8;
#pragma unroll
      for (int j = 0; j < 4; ++j) {
        bf16x8 vv = *(const bf16x8*)(T + (size_t)dvrow * 272 + (tid & 3) * 16 + j * 64);
        *(bf16x8*)(dst + j * 32) = vv;
      }
    }
  } else {
    const float qscale = 0.18033688f;  // 0.125 / ln(2): scores*0.125 via exp2
#pragma unroll
    for (int mt = 0; mt < 4; ++mt) {
#pragma unroll
      for (int nt = 0; nt < 4; ++nt) {
        f32x4 v = acc[mt][nt];
        if (z == 0) {
#pragma unroll
          for (int g = 0; g < 4; ++g) v[g] *= qscale;
        }
        int col = n0 + wn * 64 + nt * 16 + r;
        int h = col >> 6, d = col & 63;
        int s = sbase + wm * 64 + mt * 16 + qd * 4;
        __bf16* O = (z == 0 ? Qo : Ko) + ((size_t)(b * 8 + h) * 2048 + s) * 64 + d;
#pragma unroll
        for (int g = 0; g < 4; ++g) O[(size_t)g * 64] = (__bf16)v[g];
      }
    }
  }
}

// ---------------- gemm_out: out[8192,512] = Ob @ WoT^T + bo, tile 64x128, grid 512 ----------------
__global__ __launch_bounds__(256, 2) void gemm_out(const __bf16* Ob, const __bf16* WoT,
                                                   const float* bo, float* out) {
  __shared__ __align__(16) __bf16 As[64 * 64];
  __shared__ __align__(16) __bf16 Bs[128 * 64];
  const int tid = threadIdx.x, lane = tid & 63, w = tid >> 6;
  const int qd = lane >> 4, r = lane & 15, wm = w & 1, wn = w >> 1;
  const int id = blockIdx.x;
  const int rest = id >> 3;
  const int m0 = ((id & 7) * 16 + (rest & 15)) * 64;
  const int n0 = (rest >> 4) * 128;
  const char* ap[2];
  const char* bp[4];
#pragma unroll
  for (int j = 0; j < 2; ++j) {
    int c = (w * 2 + j) * 64 + lane;
    int row = c >> 3, gc = (c & 7) ^ (row & 7);
    ap[j] = (const char*)Ob + (size_t)(m0 + row) * 1024 + gc * 16;
  }
#pragma unroll
  for (int j = 0; j < 4; ++j) {
    int c = (w * 4 + j) * 64 + lane;
    int row = c >> 3, gc = (c & 7) ^ (row & 7);
    bp[j] = (const char*)WoT + (size_t)(n0 + row) * 1024 + gc * 16;
  }
  int offA[2][2], offB[4][2];
#pragma unroll
  for (int ks = 0; ks < 2; ++ks) {
#pragma unroll
    for (int t = 0; t < 2; ++t) {
      int m = wm * 32 + t * 16 + r;
      offA[t][ks] = m * 128 + (((ks * 4 + qd) ^ (m & 7)) * 16);
    }
#pragma unroll
    for (int t = 0; t < 4; ++t) {
      int n = wn * 64 + t * 16 + r;
      offB[t][ks] = n * 128 + (((ks * 4 + qd) ^ (n & 7)) * 16);
    }
  }
  char* AsC = (char*)As;
  char* BsC = (char*)Bs;
  f32x4 acc[2][4] = {};
  for (int kt = 0; kt < 8; ++kt) {
    __syncthreads();
#pragma unroll
    for (int j = 0; j < 2; ++j) gld16(ap[j] + kt * 128, AsC + (w * 2 + j) * 1024);
#pragma unroll
    for (int j = 0; j < 4; ++j) gld16(bp[j] + kt * 128, BsC + (w * 4 + j) * 1024);
    __syncthreads();
#pragma unroll
    for (int ks = 0; ks < 2; ++ks) {
      bf16x8 a[2], b[4];
#pragma unroll
      for (int t = 0; t < 2; ++t) a[t] = *(const bf16x8*)(AsC + offA[t][ks]);
#pragma unroll
      for (int t = 0; t < 4; ++t) b[t] = *(const bf16x8*)(BsC + offB[t][ks]);
#pragma unroll
      for (int i = 0; i < 2; ++i)
#pragma unroll
        for (int j2 = 0; j2 < 4; ++j2)
          acc[i][j2] = __builtin_amdgcn_mfma_f32_16x16x32_bf16(a[i], b[j2], acc[i][j2], 0, 0, 0);
    }
  }
#pragma unroll
  for (int nt = 0; nt < 4; ++nt) {
    int col = n0 + wn * 64 + nt * 16 + r;
    float bv = bo[col];
#pragma unroll
    for (int mt = 0; mt < 2; ++mt) {
      int mg = m0 + wm * 32 + mt * 16 + qd * 4;
#pragma unroll
      for (int g = 0; g < 4; ++g) out[(size_t)(mg + g) * 512 + col] = acc[mt][nt][g] + bv;
    }
  }
}

// ---------------- attention ----------------
// Grid 1024 = 8 XCD x (4 bh x 2 kv-halves x 16 q-tiles), 4 resident blocks/CU (LDS 32KB), one
// round, no tail. Q-tile 128, KV-tile 64, 16 iters. S^T = K·Q^T so P exits with keys on the
// per-lane reg axis -> packed bf16x4 LDS writes. Ps OVERLAYS Qs (dead after frag preload),
// 128B row stride + XOR-16B swizzle (gemm-tile pattern, 2-way max conflicts). Row sums via
// MFMA against a ones B-operand (no VALU adds, no end shuffles; layout matches O write).
__global__ __launch_bounds__(256, 4) void attn(const __bf16* Q, const __bf16* K,
                                               const __bf16* Vt, __bf16* Opart, float* Lp) {
  __shared__ __align__(16) __bf16 QPs[128 * 64];  // Qs during preload, Ps during loop
  __shared__ __align__(16) __bf16 Ks[64 * 64];
  __shared__ __align__(16) __bf16 Vs[64 * 64];
  const int tid = threadIdx.x, lane = tid & 63, w = tid >> 6;
  const int qd = lane >> 4, r = lane & 15;
  const int id = blockIdx.x;
  const int rest = id >> 3;
  const int bh = (id & 7) * 4 + (rest >> 5);
  const int kvh = (rest >> 4) & 1;
  const int q0 = (rest & 15) * 128;
  const __bf16* Qg = Q + ((size_t)bh * 2048 + q0) * 64;
  const __bf16* Kg = K + (size_t)bh * 2048 * 64;
  const __bf16* Vg = Vt + (size_t)bh * 64 * 2048;
  char* PsC = (char*)QPs;
  char* KsC = (char*)Ks;
  char* VsC = (char*)Vs;

  // stage Q tile (16KB) into QPs
#pragma unroll
  for (int j = 0; j < 4; ++j) {
    int c = (w * 4 + j) * 64 + lane;
    int m = c >> 3, gc = (c & 7) ^ (m & 7);
    gld16((const char*)Qg + m * 128 + gc * 16, PsC + (w * 4 + j) * 1024);
  }
  __syncthreads();

  // Q fragments (B-operand: n=q on lane&15, k=d on qd*8+j)
  bf16x8 qf[2][2];
#pragma unroll
  for (int mt = 0; mt < 2; ++mt)
#pragma unroll
    for (int ks = 0; ks < 2; ++ks) {
      int m = w * 32 + mt * 16 + r;
      qf[mt][ks] = *(const bf16x8*)(PsC + m * 128 + ((ks * 4 + qd) ^ (m & 7)) * 16);
    }

  int offKV[4][2];
#pragma unroll
  for (int t = 0; t < 4; ++t)
#pragma unroll
    for (int ks = 0; ks < 2; ++ks) {
      int n = t * 16 + r;
      offKV[t][ks] = n * 128 + ((ks * 4 + qd) ^ (n & 7)) * 16;
    }

  bf16x8 ones;
#pragma unroll
  for (int j = 0; j < 8; ++j) ones[j] = (__bf16)1.0f;

  f32x4 oacc[2][4] = {};
  f32x4 lacc[2] = {};

  const int kt0 = kvh * 16;
  for (int kt = kt0; kt < kt0 + 16; ++kt) {
    __syncthreads();  // also separates qf/Ps reads of prev iter from this iter's Ps writes
#pragma unroll
    for (int j = 0; j < 2; ++j) {
      int c = (w * 2 + j) * 64 + lane;
      int m = c >> 3, gc = (c & 7) ^ (m & 7);
      gld16((const char*)Kg + (size_t)(kt * 64 + m) * 128 + gc * 16, KsC + (w * 2 + j) * 1024);
      gld16((const char*)Vg + (size_t)m * 4096 + kt * 128 + gc * 16, VsC + (w * 2 + j) * 1024);
    }
    __syncthreads();

    // S^T = K · Q^T : D[m=key][n=q]  (A=K frags, B=Q frags)
    f32x4 sf[2][4] = {};
#pragma unroll
    for (int nt = 0; nt < 4; ++nt) {
      bf16x8 kf0 = *(const bf16x8*)(KsC + offKV[nt][0]);
      bf16x8 kf1 = *(const bf16x8*)(KsC + offKV[nt][1]);
#pragma unroll
      for (int mt = 0; mt < 2; ++mt) {
        sf[mt][nt] = __builtin_amdgcn_mfma_f32_16x16x32_bf16(kf0, qf[mt][0], sf[mt][nt], 0, 0, 0);
        sf[mt][nt] = __builtin_amdgcn_mfma_f32_16x16x32_bf16(kf1, qf[mt][1], sf[mt][nt], 0, 0, 0);
      }
    }
    // exp2 + packed P write into swizzled Ps (lane holds keys nt*16+qd*4+{0..3} of q-row)
#pragma unroll
    for (int mt = 0; mt < 2; ++mt) {
      int q = w * 32 + mt * 16 + r;
#pragma unroll
      for (int nt = 0; nt < 4; ++nt) {
        bf16x4 p4;
#pragma unroll
        for (int g = 0; g < 4; ++g) p4[g] = (__bf16)__builtin_exp2f(sf[mt][nt][g]);
        *(bf16x4*)(PsC + q * 128 + (((2 * nt + (qd >> 1)) ^ (q & 7)) * 16) + (qd & 1) * 8) = p4;
      }
    }
    // O += P V ; rowsum via MFMA(P, ones). P rows wave-private: write->read via lgkmcnt only.
#pragma unroll
    for (int mt = 0; mt < 2; ++mt) {
      int q = w * 32 + mt * 16 + r;
      bf16x8 pf0 = *(const bf16x8*)(PsC + q * 128 + ((qd ^ (q & 7)) * 16));
      bf16x8 pf1 = *(const bf16x8*)(PsC + q * 128 + (((4 + qd) ^ (q & 7)) * 16));
      lacc[mt] = __builtin_amdgcn_mfma_f32_16x16x32_bf16(pf0, ones, lacc[mt], 0, 0, 0);
      lacc[mt] = __builtin_amdgcn_mfma_f32_16x16x32_bf16(pf1, ones, lacc[mt], 0, 0, 0);
#pragma unroll
      for (int dvt = 0; dvt < 4; ++dvt) {
        bf16x8 vf0 = *(const bf16x8*)(VsC + offKV[dvt][0]);
        bf16x8 vf1 = *(const bf16x8*)(VsC + offKV[dvt][1]);
        oacc[mt][dvt] = __builtin_amdgcn_mfma_f32_16x16x32_bf16(pf0, vf0, oacc[mt][dvt], 0, 0, 0);
        oacc[mt][dvt] = __builtin_amdgcn_mfma_f32_16x16x32_bf16(pf1, vf1, oacc[mt][dvt], 0, 0, 0);
      }
    }
  }

  // lacc[mt][g] = rowsum(q = w*32+mt*16+qd*4+g), identical across r lanes
  const size_t pbase = (size_t)(kvh * 32 + bh) * 2048;
#pragma unroll
  for (int mt = 0; mt < 2; ++mt) {
    if (r == 0) {
#pragma unroll
      for (int g = 0; g < 4; ++g)
        Lp[pbase + q0 + w * 32 + mt * 16 + qd * 4 + g] = lacc[mt][g];
    }
  }
  // unnormalized O partial (bf16): lane holds q = w*32+mt*16+qd*4+g, dv = dvt*16+r
  __bf16* Ob0 = Opart + pbase * 64;
#pragma unroll
  for (int mt = 0; mt < 2; ++mt) {
#pragma unroll
    for (int g = 0; g < 4; ++g) {
      int s = q0 + w * 32 + mt * 16 + qd * 4 + g;
#pragma unroll
      for (int dvt = 0; dvt < 4; ++dvt)
        Ob0[(size_t)s * 64 + dvt * 16 + r] = (__bf16)oacc[mt][dvt][g];
    }
  }
}

// combine the two kv-half partials -> Ob[b][s][h*64+dv] bf16
__global__ __launch_bounds__(256) void combine(const __bf16* Op, const float* Lp, __bf16* Ob) {
  int c = blockIdx.x * 256 + threadIdx.x;  // 524288 chunks of 8 elems
  int bhs = c >> 3;
  int dv0 = (c & 7) * 8;
  size_t e = (size_t)bhs * 64 + dv0;
  bf16x8 a = *(const bf16x8*)(Op + e);
  bf16x8 b2 = *(const bf16x8*)(Op + ((size_t)32 * 2048 * 64) + e);
  float inv = 1.0f / (Lp[bhs] + Lp[bhs + 65536]);
  int bh = bhs >> 11, s = bhs & 2047, b = bh >> 3, h = bh & 7;
  bf16x8 o;
#pragma unroll
  for (int j = 0; j < 8; ++j) o[j] = (__bf16)(((float)a[j] + (float)b2[j]) * inv);
  *(bf16x8*)(Ob + ((size_t)(b * 2048 + s)) * 512 + h * 64 + dv0) = o;
}

// ---------------- host ----------------

extern "C" void kernel_launch(void* const* d_in, const int* in_sizes, int n_in,
                              void* d_out, int out_size, void* d_ws, size_t ws_size,
                              hipStream_t stream) {
  const float* x1 = (const float*)d_in[0];
  const float* x2 = (const float*)d_in[1];
  const float* x3 = (const float*)d_in[2];
  const float* Wq = (const float*)d_in[3];
  const float* Wk = (const float*)d_in[4];
  const float* Wv = (const float*)d_in[5];
  const float* Wo = (const float*)d_in[6];
  const float* bo = (const float*)d_in[7];
  float* out = (float*)d_out;
  char* ws = (char*)d_ws;
  const size_t MB = 1ull << 20;
  __bf16* x1b = (__bf16*)(ws);
  __bf16* x2b = (__bf16*)(ws + 8 * MB);
  __bf16* x3b = (__bf16*)(ws + 16 * MB);
  __bf16* WT = (__bf16*)(ws + 24 * MB);
  __bf16* Qb = (__bf16*)(ws + 26 * MB);
  __bf16* Kb = (__bf16*)(ws + 34 * MB);
  __bf16* Vtb = (__bf16*)(ws + 42 * MB);
  __bf16* Ob = (__bf16*)(ws + 50 * MB);
  __bf16* Opart = (__bf16*)(ws + 58 * MB);
  float* Lp = (float*)(ws + 74 * MB);

  cvt_all<<<dim3(12544), 256, 0, stream>>>(x1, x2, x3, Wq, Wk, Wv, Wo, x1b, x2b, x3b, WT);
  gemm_proj<<<dim3(256, 1, 3), 256, 0, stream>>>(x1b, x2b, x3b, WT, Qb, Kb, Vtb);
  attn<<<dim3(1024), 256, 0, stream>>>(Qb, Kb, Vtb, Opart, Lp);
  combine<<<dim3(2048), 256, 0, stream>>>(Opart, Lp, Ob);
  gemm_out<<<dim3(512), 256, 0, stream>>>(Ob, WT + 3ull * 512 * 512, bo, out);
}